// Round 10
// baseline (213.670 us; speedup 1.0000x reference)
//
#include <hip/hip_runtime.h>
#include <math.h>

#define NN 10000
#define EE 160000
#define EP 170000          // EE + NN self loops
#define NFEAT 256
#define NHID 128
#define NH 4
#define HF 512             // NH * NHID
#define NCLASS 40

// [R10: R8/R9 masked-chunk agg abandoned — 4 consecutive container failures for that
//  source vs first-try passes for neighbors => source-correlated crash, unmeasurable.
//  This round: EXACT R2-proven agg loop (passed 3x, 206.5us) + only arithmetic-identical
//  micro-deltas (32-bit gather offsets, fmaxf-leaky, __expf ELU — all proven in R7).]
// [Session model: dur = F(~130us harness poison fills, immovable) + ours(~76us);
//  agg 2x24.5us, GEMMs ~13us, setup/CSR ~13us. agg structural attacks (fused-head R7,
//  masked chunks R8) both failed; likely L2-gather-throughput/latency floor ~17-25us.]

typedef __attribute__((ext_vector_type(8))) short bf8;     // 8 bf16 (4 VGPR) MFMA frag
typedef __attribute__((ext_vector_type(8))) unsigned short u16x8;
typedef __attribute__((ext_vector_type(4))) float f4;

__device__ __forceinline__ float leaky02(float x) { return fmaxf(x, 0.2f * x); }

__device__ __forceinline__ unsigned short f2bf(float f) {   // RNE
    unsigned u = __builtin_bit_cast(unsigned, f);
    unsigned r = (u + 0x7FFF + ((u >> 16) & 1)) >> 16;
    return (unsigned short)r;
}
__device__ __forceinline__ float bf2f(unsigned short h) {
    return __builtin_bit_cast(float, (unsigned)h << 16);
}

// Bank-swizzled element position within a row of length K (baked into GLOBAL layout
// of MFMA operands so global->LDS staging is a LINEAR copy for global_load_lds).
__device__ __forceinline__ int swz(int row, int c) {
    return ((((c >> 3) ^ (row & 7)) << 3) | (c & 7));
}

// 16B global -> LDS direct DMA
__device__ __forceinline__ void gl_lds16(const unsigned short* g, unsigned short* l)
{
    __builtin_amdgcn_global_load_lds(
        (const __attribute__((address_space(1))) unsigned int*)g,
        (__attribute__((address_space(3))) unsigned int*)l, 16, 0, 0);
}

// ---------------- fused setup: cvt fw+dw (bf16, swizzled) + biasRG + edge count ----------
// [R3 lesson: range-owner count (8 blocks x full edge scan) = 251us latency disaster.
//  Grid-stride count over 120 blocks + memset-zeroed cnt.]
#define CVT_EL 136192              // 131072 (gat_w+res_w) + 5120 (dec_w)
#define CVT_B  67                  // ceil((CVT_EL/8)/256)
#define TOT_B  188                 // CVT_B + 1 (bias/pad) + 120 count blocks

__global__ __launch_bounds__(256)
void fused0_k(const float* __restrict__ gat_w, const float* __restrict__ res_w,
              const float* __restrict__ dec_w,
              const float* __restrict__ res_b, const float* __restrict__ gat_b,
              const int* __restrict__ ei,
              unsigned short* __restrict__ fwhi, unsigned short* __restrict__ dwhi,
              float* __restrict__ biasRG, int* __restrict__ cnt)
{
    int bId = blockIdx.x, t = threadIdx.x;
    if (bId < CVT_B) {
        int iu = bId * 256 + t;
        int i = iu * 8;
        if (i >= CVT_EL) return;
        const float* src; unsigned short* ph; int j;
        if (i < 131072) { j = i;          ph = fwhi;
                          src = (j < 65536) ? (gat_w + j) : (res_w + j - 65536); }
        else            { j = i - 131072; ph = dwhi; src = dec_w + j; }
        int row = j >> 7, c = j & 127;
        float4 v0 = *(const float4*)src, v1 = *(const float4*)(src + 4);
        float vv[8] = {v0.x, v0.y, v0.z, v0.w, v1.x, v1.y, v1.z, v1.w};
        unsigned short hs[8];
#pragma unroll
        for (int k = 0; k < 8; ++k) hs[k] = f2bf(vv[k]);
        *(u16x8*)(ph + row * 128 + swz(row, c)) = *(u16x8*)hs;
    } else if (bId == CVT_B) {
        biasRG[t]       = res_b[t]       + gat_b[t];
        biasRG[t + 256] = res_b[t + 256] + gat_b[t + 256];
        u16x8 z = {0, 0, 0, 0, 0, 0, 0, 0};
        for (int i = t; i < 384; i += 256)                 // dec pad rows 40..63
            *(u16x8*)(dwhi + 40 * 128 + i * 8) = z;
    } else {
        for (int e = (bId - CVT_B - 1) * 256 + t; e < EP; e += 120 * 256) {
            int d = (e < EE) ? ei[EE + e] : (e - EE);
            atomicAdd(&cnt[d], 1);
        }
    }
}

// ---------------- bf16 MFMA GEMM (BM=64 x BN tile) + LDS-staged epilogue ----------------
// 4 waves 2x2; wave tile 32 x BN/2. acc += A*B (plain bf16).
// F32=true: A,B fp32 row-major (natural); reg-stage + cvt + swizzled ds_write.
// F32=false: A,B bf16 with swizzle baked in global layout; linear global_load_lds.
// MODE 0: dec (BN=64) -> outF[row*40+col]+bias (scalar, 40 cols)
// MODE 1: enc (BN=128)-> relu(v+bias) -> bf16 (swizzled), ld=128
// MODE 2: layer(BN=128)-> y<4: bf16 xh (natural) + attn dot (plain store, full head/block);
//                         y>=4: bf16 res+biasRG (natural)
// MERGE 1: last y-slice x==0 runs CSR prefix scan (writes row_ptr AND cursor=row_ptr);
// MERGE 2: last y-slice fills CSR via atomicAdd(cursor).
template<int MODE, int KTILES, int MERGE, bool F32, int BN>
__global__ __launch_bounds__(256)
void gemm3_k(const void* __restrict__ Ap, const void* __restrict__ Bp,
             const float* __restrict__ bias, float* __restrict__ outF,
             unsigned short* __restrict__ outH, unsigned short* __restrict__ outL,
             float* __restrict__ aS, float* __restrict__ aD,
             const float* __restrict__ attS, const float* __restrict__ attD, int M,
             const int* __restrict__ ei, const int* __restrict__ cnt,
             int* __restrict__ row_ptr, int* __restrict__ cursor, int* __restrict__ csr)
{
    constexpr int K  = KTILES * 128;
    constexpr int JT = BN / 32;                 // B MFMA-tiles per wave
    constexpr int TU = 1024 + BN * 16;          // 8-elem staging units per k-tile
    constexpr int CW = BN / 4;                  // epilogue cols per thread
    constexpr int BNP = BN + 4;                 // sC padded stride
    __shared__ __align__(16) unsigned short smem[8192 + BN * 128];
    const int tid = threadIdx.x;

    if (MERGE && blockIdx.y == gridDim.y - 1) {
        if (MERGE == 1) {
            if (blockIdx.x != 0) return;
            int* smi = (int*)smem;
            int i0 = tid * 40, i1 = min(i0 + 40, NN);
            int part = 0;
            for (int i = i0; i < i1; ++i) part += cnt[i];
            smi[tid] = part;
            __syncthreads();
            for (int off = 1; off < 256; off <<= 1) {
                int v = (tid >= off) ? smi[tid - off] : 0;
                __syncthreads();
                smi[tid] += v;
                __syncthreads();
            }
            int run = smi[tid] - part;
            for (int i = i0; i < i1; ++i) {
                row_ptr[i] = run; cursor[i] = run; run += cnt[i];
            }
            if (tid == 255) row_ptr[NN] = run;
        } else {
            int stride = gridDim.x * 256;
            for (int e = blockIdx.x * 256 + tid; e < EP; e += stride) {
                int s, d;
                if (e < EE) { s = ei[e]; d = ei[EE + e]; } else { s = e - EE; d = s; }
                int pos = atomicAdd(&cursor[d], 1);       // starts at row_ptr[d]
                csr[pos] = s;
            }
        }
        return;
    }

    unsigned short* sA = smem;
    unsigned short* sB = smem + 8192;

    const int lane = tid & 63, wv = tid >> 6;
    const int wr = (wv >> 1) * 32, wc = (wv & 1) * (BN / 2);
    const int bm = blockIdx.x * 64, bn = blockIdx.y * BN;
    const int r16 = lane & 15, q4 = lane >> 4;
    const int ra0 = wr + r16;
    const int rb0 = wc + r16;
    const int rbase = q4 * 4;

    f4 acc[2][JT];
#pragma unroll
    for (int i = 0; i < 2; ++i)
#pragma unroll
        for (int j = 0; j < JT; ++j) acc[i][j] = (f4){0.f, 0.f, 0.f, 0.f};

    for (int kt = 0; kt < KTILES; ++kt) {
        if (kt) __syncthreads();
        if (!F32) {
            const unsigned short* A = (const unsigned short*)Ap;
            const unsigned short* B = (const unsigned short*)Bp;
#pragma unroll
            for (int j = 0; j < TU / 256; ++j) {
                int i = tid + j * 256;
                if (j < 4) {                          // A units 0..1023
                    int row = i >> 4, u = i & 15;
                    size_t ga = (size_t)min(bm + row, M - 1) * K + kt * 128 + u * 8;
                    int lb = (wv * 64 + j * 256) * 8; // wave-uniform LDS base
                    gl_lds16(A + ga, sA + lb);
                } else {                              // B units
                    int ib = i - 1024;
                    int row = ib >> 4, u = ib & 15;
                    size_t gb = (size_t)(bn + row) * K + kt * 128 + u * 8;
                    int lb = (wv * 64 + (j - 4) * 256) * 8;
                    gl_lds16(B + gb, sB + lb);
                }
            }
        } else {
            const float* A = (const float*)Ap;
            const float* B = (const float*)Bp;
#pragma unroll
            for (int j = 0; j < TU / 256; ++j) {
                int i = tid + j * 256;
                const float* src; unsigned short* dst; int row, u;
                if (j < 4) { row = i >> 4; u = i & 15; dst = sA;
                             src = A + (size_t)min(bm + row, M - 1) * K + kt * 128 + u * 8; }
                else       { int ib = i - 1024; row = ib >> 4; u = ib & 15; dst = sB;
                             src = B + (size_t)(bn + row) * K + kt * 128 + u * 8; }
                float4 v0 = *(const float4*)src, v1 = *(const float4*)(src + 4);
                float vv[8] = {v0.x, v0.y, v0.z, v0.w, v1.x, v1.y, v1.z, v1.w};
                unsigned short hs[8];
#pragma unroll
                for (int k = 0; k < 8; ++k) hs[k] = f2bf(vv[k]);
                int off = row * 128 + ((u ^ (row & 7)) * 8);   // local-row swizzle slot
                *(u16x8*)(dst + off) = *(u16x8*)hs;
            }
        }
        __syncthreads();

#pragma unroll
        for (int ks = 0; ks < 4; ++ks) {
            int u = ks * 4 + q4;
            bf8 Af[2], Bf[JT];
#pragma unroll
            for (int i = 0; i < 2; ++i)
                Af[i] = *(const bf8*)(sA + (ra0 + 16 * i) * 128 + ((u ^ (ra0 & 7)) * 8));
#pragma unroll
            for (int j = 0; j < JT; ++j)
                Bf[j] = *(const bf8*)(sB + (rb0 + 16 * j) * 128 + ((u ^ (rb0 & 7)) * 8));
#pragma unroll
            for (int i = 0; i < 2; ++i)
#pragma unroll
                for (int j = 0; j < JT; ++j)
                    acc[i][j] = __builtin_amdgcn_mfma_f32_16x16x32_bf16(
                        Af[i], Bf[j], acc[i][j], 0, 0, 0);
        }
    }

    if (MODE == 0) {
        // scalar epilogue: dec (40 cols), BN=64
#pragma unroll
        for (int i = 0; i < 2; ++i)
#pragma unroll
            for (int j = 0; j < JT; ++j)
#pragma unroll
                for (int r = 0; r < 4; ++r) {
                    int row = bm + wr + i * 16 + rbase + r;
                    int col = bn + wc + j * 16 + r16;
                    if (row >= M || col >= NCLASS) continue;
                    outF[(size_t)row * NCLASS + col] = acc[i][j][r] + bias[col];
                }
        return;
    }

    // ---- staged coalesced epilogue ----
    __syncthreads();
    float* sC = (float*)smem;                 // 64 x BNP fp32
#pragma unroll
    for (int i = 0; i < 2; ++i)
#pragma unroll
        for (int j = 0; j < JT; ++j)
#pragma unroll
            for (int r = 0; r < 4; ++r)
                sC[(wr + i * 16 + rbase + r) * BNP + (wc + j * 16 + r16)] = acc[i][j][r];
    __syncthreads();

    int row = tid >> 2, seg = tid & 3, c0 = seg * CW;
    int grow = bm + row;
    if (grow < M) {
        float v[CW];
#pragma unroll
        for (int k = 0; k < CW; ++k) v[k] = sC[row * BNP + c0 + k];

        if (MODE == 1) {                      // enc: relu+bias -> Xhi (swizzled, ld=128)
            unsigned short hs[CW];
#pragma unroll
            for (int k = 0; k < CW; ++k)
                hs[k] = f2bf(fmaxf(v[k] + bias[bn + c0 + k], 0.0f));
#pragma unroll
            for (int uu = 0; uu < CW / 8; ++uu) {
                int ug = (bn + c0) / 8 + uu;
                int pu = ug ^ (grow & 7);
                *(u16x8*)(outH + (size_t)grow * 128 + pu * 8) = *(u16x8*)(hs + uu * 8);
            }
        } else {                              // MODE 2 (BN=128: head or res-half per block)
            if (bn < 512) {                   // xh -> bf16 (natural) + full-head attn dot
                unsigned short hs[CW];
#pragma unroll
                for (int k = 0; k < CW; ++k) hs[k] = f2bf(v[k]);
#pragma unroll
                for (int uu = 0; uu < CW / 8; ++uu)
                    *(u16x8*)(outH + (size_t)grow * 512 + bn + c0 + uu * 8)
                        = *(u16x8*)(hs + uu * 8);
                float ps = 0.0f, pd = 0.0f;
#pragma unroll
                for (int k = 0; k < CW; ++k) {
                    ps = fmaf(v[k], attS[bn + c0 + k], ps);
                    pd = fmaf(v[k], attD[bn + c0 + k], pd);
                }
                ps += __shfl_xor(ps, 1); ps += __shfl_xor(ps, 2);
                pd += __shfl_xor(pd, 1); pd += __shfl_xor(pd, 2);
                if (seg == 0) {               // single writer per (row, head): plain store
                    int h = bn >> 7;
                    aS[grow * 4 + h] = ps;
                    aD[grow * 4 + h] = pd;
                }
            } else {                          // res + (res_b+gat_b) -> bf16 (natural)
                unsigned short hs[CW];
#pragma unroll
                for (int k = 0; k < CW; ++k)
                    hs[k] = f2bf(v[k] + bias[bn - 512 + c0 + k]);
#pragma unroll
                for (int uu = 0; uu < CW / 8; ++uu)
                    *(u16x8*)(outL + (size_t)grow * 512 + (bn - 512) + c0 + uu * 8)
                        = *(u16x8*)(hs + uu * 8);
            }
        }
    }
}

// ------- head-partitioned softmax+gather+residual+ELU+quad-mean -> X (bf16, swizzled) ------
// EXACT R2-proven loop structure (passed 3x at ~206.5us): head h = bx/2500 (head-major
// -> 2.56MB xh slice per dispatch quarter, per-XCD L2 resident). Wave per (node, head);
// lanes = 4 edge-subgroups x 16 col-lanes; 16-edge main loop + 4-edge mid + predicated
// tail; cross-subgroup combine via shfl_xor. Only arithmetic-identical micro-deltas:
// 32-bit gather offsets, fmaxf-leaky, __expf-1 ELU.
__global__ __launch_bounds__(256)
void agg_k(const int* __restrict__ row_ptr, const int* __restrict__ csr,
           const float* __restrict__ a_src, const float* __restrict__ a_dst,
           const unsigned short* __restrict__ xh_b, const unsigned short* __restrict__ resb,
           unsigned short* __restrict__ Xhi)
{
    int bx = blockIdx.x;
    int h  = bx / 2500;
    int ng = bx - h * 2500;
    int wv = threadIdx.x >> 6, lane = threadIdx.x & 63;
    int d = ng * 4 + wv;                      // 2500*4 = NN exact
    int beg = row_ptr[d], end = row_ptr[d + 1];
    int eg = lane >> 4, c16 = lane & 15;      // edge subgroup / col lane
    unsigned cb = (unsigned)(h * 128 + c16 * 8);   // 8 cols of head h
    float ad = a_dst[d * 4 + h];
    u16x8 rv = *(const u16x8*)(resb + (size_t)d * HF + cb);

    float acc[8];
#pragma unroll
    for (int k = 0; k < 8; ++k) acc[k] = 0.0f;
    float ssum = 0.0f;

    int e = beg;
    for (; e + 16 <= end; e += 16) {          // 4 chunks x 4 edges in flight
        int sv[4]; float w[4]; u16x8 v[4];
#pragma unroll
        for (int q = 0; q < 4; ++q) sv[q] = csr[e + q * 4 + eg];
#pragma unroll
        for (int q = 0; q < 4; ++q)
            v[q] = *(const u16x8*)(xh_b + ((unsigned)(sv[q] * HF) + cb));
#pragma unroll
        for (int q = 0; q < 4; ++q) {
            w[q] = __expf(leaky02(a_src[sv[q] * 4 + h] + ad));
            ssum += w[q];
        }
#pragma unroll
        for (int q = 0; q < 4; ++q)
#pragma unroll
            for (int k = 0; k < 8; ++k) acc[k] = fmaf(w[q], bf2f(v[q][k]), acc[k]);
    }
    for (; e + 4 <= end; e += 4) {
        int s = csr[e + eg];
        u16x8 v = *(const u16x8*)(xh_b + ((unsigned)(s * HF) + cb));
        float w = __expf(leaky02(a_src[s * 4 + h] + ad));
        ssum += w;
#pragma unroll
        for (int k = 0; k < 8; ++k) acc[k] = fmaf(w, bf2f(v[k]), acc[k]);
    }
    if (e + eg < end) {                       // predicated tail (<4 edges)
        int s = csr[e + eg];
        u16x8 v = *(const u16x8*)(xh_b + ((unsigned)(s * HF) + cb));
        float w = __expf(leaky02(a_src[s * 4 + h] + ad));
        ssum += w;
#pragma unroll
        for (int k = 0; k < 8; ++k) acc[k] = fmaf(w, bf2f(v[k]), acc[k]);
    }

    // combine the 4 edge-subgroups (lanes differing in bits 4..5)
#pragma unroll
    for (int off = 16; off <= 32; off <<= 1) {
        ssum += __shfl_xor(ssum, off);
#pragma unroll
        for (int k = 0; k < 8; ++k) acc[k] += __shfl_xor(acc[k], off);
    }

    float inv = 1.0f / ssum;
    float uv[8];
#pragma unroll
    for (int k = 0; k < 8; ++k) {
        float t = fmaf(acc[k], inv, bf2f(rv[k]));
        uv[k] = (t > 0.0f) ? t : (__expf(t) - 1.0f);   // ELU (bf16-out safe)
    }
    float z0 = (uv[0] + uv[1] + uv[2] + uv[3]) * 0.25f;
    float z1 = (uv[4] + uv[5] + uv[6] + uv[7]) * 0.25f;
    if (eg == 0) {
        int col = h * 32 + c16 * 2;           // z-cols of head h (2 per lane, same unit)
        unsigned short h0b = f2bf(z0), h1b = f2bf(z1);
        size_t idx = (size_t)d * NHID + swz(d, col);
        *(unsigned*)(Xhi + idx) = ((unsigned)h1b << 16) | h0b;
    }
}

// ---------------- launcher ----------------
extern "C" void kernel_launch(void* const* d_in, const int* in_sizes, int n_in,
                              void* d_out, int out_size, void* d_ws, size_t ws_size,
                              hipStream_t stream)
{
    const float* x       = (const float*)d_in[0];
    const int*   ei      = (const int*)d_in[1];
    const float* enc_w   = (const float*)d_in[2];
    const float* enc_b   = (const float*)d_in[3];
    const float* res_w   = (const float*)d_in[4];
    const float* res_b   = (const float*)d_in[5];
    const float* gat_w   = (const float*)d_in[6];
    const float* att_src = (const float*)d_in[7];
    const float* att_dst = (const float*)d_in[8];
    const float* gat_b   = (const float*)d_in[9];
    const float* dec_w   = (const float*)d_in[10];
    const float* dec_b   = (const float*)d_in[11];
    float* out = (float*)d_out;

    char* p = (char*)d_ws;
    auto alloc = [&](size_t bytes) -> void* {
        void* r = (void*)p;
        p += (bytes + 255) & ~(size_t)255;
        return r;
    };
    float* biasRG = (float*)alloc(512 * 4);
    unsigned short* xh_b = (unsigned short*)alloc(5120000 * 2);     // [N,512] bf16 (natural)
    unsigned short* resb = (unsigned short*)alloc(5120000 * 2);     // [N,512] bf16 (natural)
    unsigned short* Xhi  = (unsigned short*)alloc(1280000 * 2);     // [N,128] bf16 (swizzled)
    unsigned short* fwhi = (unsigned short*)alloc(1024 * 128 * 2);  // gat_w+res_w (swizzled)
    unsigned short* dwhi = (unsigned short*)alloc(8192 * 2);        // [64,128] padded (swizzled)
    int* row_ptr = (int*)alloc(10004 * 4);
    int* csr     = (int*)alloc(170000 * 4);
    int* cnt     = (int*)alloc(10000 * 4);
    int* cursor  = (int*)alloc(10000 * 4);
    float* aS    = (float*)alloc(40000 * 4);
    float* aD    = (float*)alloc(40000 * 4);

    hipMemsetAsync(cnt, 0, NN * sizeof(int), stream);   // only cnt needs pre-zero

    // setup: weight conversions + biasRG + dec pad zero + distributed degree count
    fused0_k<<<TOT_B, 256, 0, stream>>>(
        gat_w, res_w, dec_w, res_b, gat_b, ei, fwhi, dwhi, biasRG, cnt);

    // encoder gemm: fp32 A/B direct, BN=128 (y=0 compute, y=1 CSR prefix scan)
    gemm3_k<1, 2, 1, true, 128><<<dim3(157, 2), 256, 0, stream>>>(
        x, enc_w, enc_b, nullptr, Xhi, nullptr, nullptr, nullptr, nullptr, nullptr, NN,
        nullptr, cnt, row_ptr, cursor, nullptr);

    // layer 1: fused gemm BN=128 (y0..3 xh+attn, y4..7 res, y8 fill_csr)
    gemm3_k<2, 1, 2, false, 128><<<dim3(157, 9), 256, 0, stream>>>(
        Xhi, fwhi, biasRG, nullptr, xh_b, resb, aS, aD, att_src, att_dst, NN,
        ei, nullptr, nullptr, cursor, csr);
    agg_k<<<10000, 256, 0, stream>>>(row_ptr, csr, aS, aD, xh_b, resb, Xhi);

    // layer 2 (plain stores fully overwrite aS/aD before agg2 reads them)
    gemm3_k<2, 1, 0, false, 128><<<dim3(157, 8), 256, 0, stream>>>(
        Xhi, fwhi, biasRG, nullptr, xh_b, resb, aS, aD, att_src, att_dst, NN,
        nullptr, nullptr, nullptr, nullptr, nullptr);
    agg_k<<<10000, 256, 0, stream>>>(row_ptr, csr, aS, aD, xh_b, resb, Xhi);

    // decoder (BN=64)
    gemm3_k<0, 1, 0, false, 64><<<dim3(157, 1), 256, 0, stream>>>(
        Xhi, dwhi, dec_b, out, nullptr, nullptr, nullptr, nullptr, nullptr, nullptr, NN,
        nullptr, nullptr, nullptr, nullptr, nullptr);
}

// Round 11
// 206.434 us; speedup vs baseline: 1.0351x; 1.0351x over previous
//
#include <hip/hip_runtime.h>
#include <math.h>

#define NN 10000
#define EE 160000
#define EP 170000          // EE + NN self loops
#define NFEAT 256
#define NHID 128
#define NH 4
#define HF 512             // NH * NHID
#define NCLASS 40

// [R11: FINAL RESTORE. Exact resubmit of the session-best Round-2 source (206.52us).
//  Session evidence: every deviation measured neutral-or-worse — BN=128 pipeline +4-7us
//  (R7/R10), fused-head agg +4 (R7), masked-chunk agg crashed (R8/R9), u32 gather offsets
//  +7 (R10), mega-kernel +548 (R1), range-owner count +249 (R3). Timed window = ~130us
//  harness poison fills (at their own 75%-HBM roofline) + ~76us our kernels (agg 2x24.5
//  at an L2-gather-latency floor that resisted 3 structural attacks; GEMMs ~13us).]

typedef __attribute__((ext_vector_type(8))) short bf8;     // 8 bf16 (4 VGPR) MFMA frag
typedef __attribute__((ext_vector_type(8))) unsigned short u16x8;
typedef __attribute__((ext_vector_type(4))) float f4;

__device__ __forceinline__ float leaky02(float x) { return x >= 0.0f ? x : 0.2f * x; }

__device__ __forceinline__ unsigned short f2bf(float f) {   // RNE
    unsigned u = __builtin_bit_cast(unsigned, f);
    unsigned r = (u + 0x7FFF + ((u >> 16) & 1)) >> 16;
    return (unsigned short)r;
}
__device__ __forceinline__ float bf2f(unsigned short h) {
    return __builtin_bit_cast(float, (unsigned)h << 16);
}

// Bank-swizzled element position within a row of length K (baked into GLOBAL layout
// of MFMA operands so global->LDS staging is a LINEAR copy for global_load_lds).
__device__ __forceinline__ int swz(int row, int c) {
    return ((((c >> 3) ^ (row & 7)) << 3) | (c & 7));
}

// 16B global -> LDS direct DMA
__device__ __forceinline__ void gl_lds16(const unsigned short* g, unsigned short* l)
{
    __builtin_amdgcn_global_load_lds(
        (const __attribute__((address_space(1))) unsigned int*)g,
        (__attribute__((address_space(3))) unsigned int*)l, 16, 0, 0);
}

// ---------------- fused setup: cvt fw+dw (bf16, swizzled) + biasRG + edge count ----------
#define CVT_EL 136192              // 131072 (gat_w+res_w) + 5120 (dec_w)
#define CVT_B  67                  // ceil((CVT_EL/8)/256)
#define TOT_B  188                 // CVT_B + 1 bias + 120 count blocks

__global__ __launch_bounds__(256)
void fused0_k(const float* __restrict__ gat_w, const float* __restrict__ res_w,
              const float* __restrict__ dec_w,
              const float* __restrict__ res_b, const float* __restrict__ gat_b,
              const int* __restrict__ ei,
              unsigned short* __restrict__ fwhi, unsigned short* __restrict__ dwhi,
              float* __restrict__ biasRG, int* __restrict__ cnt)
{
    int bId = blockIdx.x, t = threadIdx.x;
    if (bId < CVT_B) {
        int iu = bId * 256 + t;
        int i = iu * 8;
        if (i >= CVT_EL) return;
        const float* src; unsigned short* ph; int j;
        if (i < 131072) { j = i;          ph = fwhi;
                          src = (j < 65536) ? (gat_w + j) : (res_w + j - 65536); }
        else            { j = i - 131072; ph = dwhi; src = dec_w + j; }
        int row = j >> 7, c = j & 127;
        float4 v0 = *(const float4*)src, v1 = *(const float4*)(src + 4);
        float vv[8] = {v0.x, v0.y, v0.z, v0.w, v1.x, v1.y, v1.z, v1.w};
        unsigned short hs[8];
#pragma unroll
        for (int k = 0; k < 8; ++k) hs[k] = f2bf(vv[k]);
        *(u16x8*)(ph + row * 128 + swz(row, c)) = *(u16x8*)hs;
    } else if (bId == CVT_B) {
        biasRG[t]       = res_b[t]       + gat_b[t];
        biasRG[t + 256] = res_b[t + 256] + gat_b[t + 256];
    } else {
        for (int e = (bId - CVT_B - 1) * 256 + t; e < EP; e += (TOT_B - CVT_B - 1) * 256) {
            int d = (e < EE) ? ei[EE + e] : (e - EE);
            atomicAdd(&cnt[d], 1);
        }
    }
}

// ---------------- bf16 MFMA GEMM (32 KB LDS) + LDS-staged epilogue ----------------
// Block 64x64, 4 waves 2x2, wave 32x32 = 2x2 MFMA tiles. acc += A*B (plain bf16).
// F32=true: A,B are fp32 row-major (natural); reg-stage + cvt + swizzled ds_write.
// F32=false: A,B are bf16 with swizzle baked in global layout; linear global_load_lds.
// MODE 0: dec  -> outF[row*40+col]+bias (scalar, 40 cols)
// MODE 1: enc  -> relu(v+bias) -> bf16 (swizzled), ld=128
// MODE 2: layer-> bn<512: bf16 xh (natural, outH) + fused attn partial (atomicAdd aS/aD);
//                 512..1023: bf16 res+biasRG (natural)
// MERGE 1: last y-slice, x==0 runs the CSR prefix scan; MERGE 2: last y-slice fills CSR.
template<int MODE, int KTILES, int MERGE, bool F32>
__global__ __launch_bounds__(256)
void gemm3_k(const void* __restrict__ Ap, const void* __restrict__ Bp,
             const float* __restrict__ bias, float* __restrict__ outF,
             unsigned short* __restrict__ outH, unsigned short* __restrict__ outL,
             float* __restrict__ aS, float* __restrict__ aD,
             const float* __restrict__ attS, const float* __restrict__ attD, int M,
             const int* __restrict__ ei, const int* __restrict__ cnt,
             int* __restrict__ row_ptr, int* __restrict__ cursor, int* __restrict__ csr)
{
    constexpr int K = KTILES * 128;
    __shared__ __align__(16) unsigned short smem[2 * 64 * 128];   // 32 KB
    const int tid = threadIdx.x;

    if (MERGE && blockIdx.y == gridDim.y - 1) {
        if (MERGE == 1) {
            if (blockIdx.x != 0) return;
            int* smi = (int*)smem;
            int i0 = tid * 40, i1 = min(i0 + 40, NN);
            int part = 0;
            for (int i = i0; i < i1; ++i) part += cnt[i];
            smi[tid] = part;
            __syncthreads();
            for (int off = 1; off < 256; off <<= 1) {
                int v = (tid >= off) ? smi[tid - off] : 0;
                __syncthreads();
                smi[tid] += v;
                __syncthreads();
            }
            int run = smi[tid] - part;
            for (int i = i0; i < i1; ++i) { row_ptr[i] = run; run += cnt[i]; }
            if (tid == 255) row_ptr[NN] = run;
        } else {
            int stride = gridDim.x * 256;
            for (int e = blockIdx.x * 256 + tid; e < EP; e += stride) {
                int s, d;
                if (e < EE) { s = ei[e]; d = ei[EE + e]; } else { s = e - EE; d = s; }
                int pos = row_ptr[d] + atomicAdd(&cursor[d], 1);
                csr[pos] = s;
            }
        }
        return;
    }

    unsigned short* sA = smem;
    unsigned short* sB = smem + 8192;

    const int lane = tid & 63, wv = tid >> 6;
    const int wr = (wv >> 1) * 32, wc = (wv & 1) * 32;
    const int bm = blockIdx.x * 64, bn = blockIdx.y * 64;
    const int r16 = lane & 15, q4 = lane >> 4;

    f4 acc[2][2];
#pragma unroll
    for (int i = 0; i < 2; ++i)
#pragma unroll
        for (int j = 0; j < 2; ++j) acc[i][j] = (f4){0.f, 0.f, 0.f, 0.f};

    const int ra0 = wr + r16;
    const int rb0 = wc + r16;

    for (int kt = 0; kt < KTILES; ++kt) {
        if (kt) __syncthreads();
        if (!F32) {
            const unsigned short* A = (const unsigned short*)Ap;
            const unsigned short* B = (const unsigned short*)Bp;
#pragma unroll
            for (int j = 0; j < 4; ++j) {
                int i = tid + j * 256;                    // unit 0..1023
                int row = i >> 4, u = i & 15;
                int arow = min(bm + row, M - 1);
                size_t ga = (size_t)arow * K + kt * 128 + u * 8;
                size_t gb = (size_t)(bn + row) * K + kt * 128 + u * 8;
                int lb = (wv * 64 + j * 256) * 8;         // wave-uniform LDS base
                gl_lds16(A + ga, sA + lb);
                gl_lds16(B + gb, sB + lb);
            }
        } else {
            const float* A = (const float*)Ap;
            const float* B = (const float*)Bp;
#pragma unroll
            for (int j = 0; j < 4; ++j) {
                int i = tid + j * 256;
                int row = i >> 4, u = i & 15;             // logical unit u
                int arow = min(bm + row, M - 1);
                const float* pa = A + (size_t)arow * K + kt * 128 + u * 8;
                const float* pb = B + (size_t)(bn + row) * K + kt * 128 + u * 8;
                float4 a0 = *(const float4*)pa, a1 = *(const float4*)(pa + 4);
                float4 b0 = *(const float4*)pb, b1 = *(const float4*)(pb + 4);
                float av[8] = {a0.x, a0.y, a0.z, a0.w, a1.x, a1.y, a1.z, a1.w};
                float bv[8] = {b0.x, b0.y, b0.z, b0.w, b1.x, b1.y, b1.z, b1.w};
                unsigned short ha[8], hb[8];
#pragma unroll
                for (int k = 0; k < 8; ++k) { ha[k] = f2bf(av[k]); hb[k] = f2bf(bv[k]); }
                int off = row * 128 + ((u ^ (row & 7)) * 8);   // local-row swizzle slot
                *(u16x8*)(sA + off) = *(u16x8*)ha;
                *(u16x8*)(sB + off) = *(u16x8*)hb;
            }
        }
        __syncthreads();

#pragma unroll
        for (int ks = 0; ks < 4; ++ks) {
            int u = ks * 4 + q4;
            int oa0 = ra0 * 128 + ((u ^ (ra0 & 7)) * 8);
            int ob0 = rb0 * 128 + ((u ^ (rb0 & 7)) * 8);
            int oa1 = oa0 + 16 * 128;
            int ob1 = ob0 + 16 * 128;
            bf8 A0 = *(const bf8*)(sA + oa0);
            bf8 A1 = *(const bf8*)(sA + oa1);
            bf8 B0 = *(const bf8*)(sB + ob0);
            bf8 B1 = *(const bf8*)(sB + ob1);

            acc[0][0] = __builtin_amdgcn_mfma_f32_16x16x32_bf16(A0, B0, acc[0][0], 0, 0, 0);
            acc[0][1] = __builtin_amdgcn_mfma_f32_16x16x32_bf16(A0, B1, acc[0][1], 0, 0, 0);
            acc[1][0] = __builtin_amdgcn_mfma_f32_16x16x32_bf16(A1, B0, acc[1][0], 0, 0, 0);
            acc[1][1] = __builtin_amdgcn_mfma_f32_16x16x32_bf16(A1, B1, acc[1][1], 0, 0, 0);
        }
    }

    const int rbase = q4 * 4;

    if (MODE == 0) {
        // scalar epilogue: dec (40 cols)
#pragma unroll
        for (int i = 0; i < 2; ++i)
#pragma unroll
            for (int j = 0; j < 2; ++j)
#pragma unroll
                for (int r = 0; r < 4; ++r) {
                    int row = bm + wr + i * 16 + rbase + r;
                    int col = bn + wc + j * 16 + r16;
                    if (row >= M || col >= NCLASS) continue;
                    outF[(size_t)row * NCLASS + col] = acc[i][j][r] + bias[col];
                }
        return;
    }

    // ---- staged coalesced epilogue ----
    __syncthreads();
    float* sC = (float*)smem;                 // 64 x 65 fp32 (16.6 KB <= 32 KB)
#pragma unroll
    for (int i = 0; i < 2; ++i)
#pragma unroll
        for (int j = 0; j < 2; ++j)
#pragma unroll
            for (int r = 0; r < 4; ++r)
                sC[(wr + i * 16 + rbase + r) * 65 + (wc + j * 16 + r16)] = acc[i][j][r];
    __syncthreads();

    int row = tid >> 2, seg = tid & 3, c0 = seg * 16;
    int grow = bm + row;
    if (grow < M) {
        float v[16];
#pragma unroll
        for (int k = 0; k < 16; ++k) v[k] = sC[row * 65 + c0 + k];

        if (MODE == 1) {
            unsigned short hs[16];
#pragma unroll
            for (int k = 0; k < 16; ++k)
                hs[k] = f2bf(fmaxf(v[k] + bias[bn + c0 + k], 0.0f));
#pragma unroll
            for (int uu = 0; uu < 2; ++uu) {
                int ug = (bn + c0) / 8 + uu;
                int pu = ug ^ (grow & 7);
                *(u16x8*)(outH + (size_t)grow * 128 + pu * 8) = *(u16x8*)(hs + uu * 8);
            }
        } else {                              // MODE 2
            if (bn < 512) {                   // xh -> bf16 (natural) + fused attn partial
                unsigned short hs[16];
#pragma unroll
                for (int k = 0; k < 16; ++k) hs[k] = f2bf(v[k]);
                *(u16x8*)(outH + (size_t)grow * 512 + bn + c0)     = *(u16x8*)hs;
                *(u16x8*)(outH + (size_t)grow * 512 + bn + c0 + 8) = *(u16x8*)(hs + 8);
                // attn partial: fp32 v . att_vec (this 64-col slice is within one head)
                float ps = 0.0f, pd = 0.0f;
#pragma unroll
                for (int k = 0; k < 16; ++k) {
                    ps = fmaf(v[k], attS[bn + c0 + k], ps);
                    pd = fmaf(v[k], attD[bn + c0 + k], pd);
                }
                ps += __shfl_xor(ps, 1); ps += __shfl_xor(ps, 2);
                pd += __shfl_xor(pd, 1); pd += __shfl_xor(pd, 2);
                if (seg == 0) {
                    int h = bn >> 7;
                    atomicAdd(&aS[grow * 4 + h], ps);
                    atomicAdd(&aD[grow * 4 + h], pd);
                }
            } else {                          // res + (res_b+gat_b) -> bf16 (natural)
                unsigned short hs[16];
#pragma unroll
                for (int k = 0; k < 16; ++k) hs[k] = f2bf(v[k] + bias[bn - 512 + c0 + k]);
                *(u16x8*)(outL + (size_t)grow * 512 + (bn - 512) + c0)     = *(u16x8*)hs;
                *(u16x8*)(outL + (size_t)grow * 512 + (bn - 512) + c0 + 8) = *(u16x8*)(hs + 8);
            }
        }
    }
}

// ------- head-partitioned softmax+gather+residual+ELU+head-mean -> X (bf16, swizzled) ------
// Block bx: head h = bx/2500 (head-major launch order -> each quarter of the dispatch
// works a 2.56 MB xh slice that fits per-XCD L2). Wave per node; lanes = 4 edge-subgroups
// x 16 col-lanes, so ONE wave-load covers 4 edges' 256B head-rows. Cross-subgroup combine
// via shfl_xor (no LDS). [R17 lesson: h=bx&3 XCD-pinning + 32-edge unroll both regress.]
__global__ __launch_bounds__(256)
void agg_k(const int* __restrict__ row_ptr, const int* __restrict__ csr,
           const float* __restrict__ a_src, const float* __restrict__ a_dst,
           const unsigned short* __restrict__ xh_b, const unsigned short* __restrict__ resb,
           unsigned short* __restrict__ Xhi)
{
    int bx = blockIdx.x;
    int h  = bx / 2500;
    int ng = bx - h * 2500;
    int wv = threadIdx.x >> 6, lane = threadIdx.x & 63;
    int d = ng * 4 + wv;                      // 2500*4 = NN exact
    int beg = row_ptr[d], end = row_ptr[d + 1];
    int eg = lane >> 4, c16 = lane & 15;      // edge subgroup / col lane
    int cb = h * 128 + c16 * 8;               // 8 cols of head h
    float ad = a_dst[d * 4 + h];
    u16x8 rv = *(const u16x8*)(resb + (size_t)d * HF + cb);

    float acc[8];
#pragma unroll
    for (int k = 0; k < 8; ++k) acc[k] = 0.0f;
    float ssum = 0.0f;

    int e = beg;
    for (; e + 16 <= end; e += 16) {          // 4 chunks x 4 edges in flight
        int sv[4]; float w[4]; u16x8 v[4];
#pragma unroll
        for (int q = 0; q < 4; ++q) sv[q] = csr[e + q * 4 + eg];
#pragma unroll
        for (int q = 0; q < 4; ++q) v[q] = *(const u16x8*)(xh_b + (size_t)sv[q] * HF + cb);
#pragma unroll
        for (int q = 0; q < 4; ++q) {
            w[q] = __expf(leaky02(a_src[sv[q] * 4 + h] + ad));
            ssum += w[q];
        }
#pragma unroll
        for (int q = 0; q < 4; ++q)
#pragma unroll
            for (int k = 0; k < 8; ++k) acc[k] = fmaf(w[q], bf2f(v[q][k]), acc[k]);
    }
    for (; e + 4 <= end; e += 4) {
        int s = csr[e + eg];
        u16x8 v = *(const u16x8*)(xh_b + (size_t)s * HF + cb);
        float w = __expf(leaky02(a_src[s * 4 + h] + ad));
        ssum += w;
#pragma unroll
        for (int k = 0; k < 8; ++k) acc[k] = fmaf(w, bf2f(v[k]), acc[k]);
    }
    if (e + eg < end) {                       // predicated tail (<4 edges)
        int s = csr[e + eg];
        u16x8 v = *(const u16x8*)(xh_b + (size_t)s * HF + cb);
        float w = __expf(leaky02(a_src[s * 4 + h] + ad));
        ssum += w;
#pragma unroll
        for (int k = 0; k < 8; ++k) acc[k] = fmaf(w, bf2f(v[k]), acc[k]);
    }

    // combine the 4 edge-subgroups (lanes differing in bits 4..5)
#pragma unroll
    for (int off = 16; off <= 32; off <<= 1) {
        ssum += __shfl_xor(ssum, off);
#pragma unroll
        for (int k = 0; k < 8; ++k) acc[k] += __shfl_xor(acc[k], off);
    }

    float inv = 1.0f / ssum;
    float uv[8];
#pragma unroll
    for (int k = 0; k < 8; ++k) {
        float v = fmaf(acc[k], inv, bf2f(rv[k]));
        uv[k] = (v > 0.0f) ? v : expm1f(v);
    }
    float z0 = (uv[0] + uv[1] + uv[2] + uv[3]) * 0.25f;
    float z1 = (uv[4] + uv[5] + uv[6] + uv[7]) * 0.25f;
    if (eg == 0) {
        int col = h * 32 + c16 * 2;           // z-cols of head h (2 per lane, same unit)
        unsigned short h0b = f2bf(z0), h1b = f2bf(z1);
        size_t idx = (size_t)d * NHID + swz(d, col);
        *(unsigned*)(Xhi + idx) = ((unsigned)h1b << 16) | h0b;
    }
}

// ---------------- launcher ----------------
extern "C" void kernel_launch(void* const* d_in, const int* in_sizes, int n_in,
                              void* d_out, int out_size, void* d_ws, size_t ws_size,
                              hipStream_t stream)
{
    const float* x       = (const float*)d_in[0];
    const int*   ei      = (const int*)d_in[1];
    const float* enc_w   = (const float*)d_in[2];
    const float* enc_b   = (const float*)d_in[3];
    const float* res_w   = (const float*)d_in[4];
    const float* res_b   = (const float*)d_in[5];
    const float* gat_w   = (const float*)d_in[6];
    const float* att_src = (const float*)d_in[7];
    const float* att_dst = (const float*)d_in[8];
    const float* gat_b   = (const float*)d_in[9];
    const float* dec_w   = (const float*)d_in[10];
    const float* dec_b   = (const float*)d_in[11];
    float* out = (float*)d_out;

    char* p = (char*)d_ws;
    auto alloc = [&](size_t bytes) -> void* {
        void* r = (void*)p;
        p += (bytes + 255) & ~(size_t)255;
        return r;
    };
    float* biasRG = (float*)alloc(512 * 4);
    unsigned short* xh_b = (unsigned short*)alloc(5120000 * 2);     // [N,512] bf16 (natural)
    unsigned short* resb = (unsigned short*)alloc(5120000 * 2);     // [N,512] bf16 (natural)
    unsigned short* Xhi  = (unsigned short*)alloc(1280000 * 2);     // [N,128] bf16 (swizzled)
    unsigned short* fwhi = (unsigned short*)alloc(1024 * 128 * 2);  // gat_w+res_w (swizzled)
    int* row_ptr = (int*)alloc(10004 * 4);
    int* csr     = (int*)alloc(170000 * 4);
    // ---- zero zone (single memset): padded dec W + cnt + cursor + attn accumulators ----
    char* zbase = p;
    unsigned short* dwhi = (unsigned short*)alloc(8192 * 2);        // [64,128] padded (swizzled)
    int* cnt    = (int*)alloc(10000 * 4);
    int* cursor = (int*)alloc(10000 * 4);
    float* aS1  = (float*)alloc(40000 * 4);
    float* aD1  = (float*)alloc(40000 * 4);
    float* aS2  = (float*)alloc(40000 * 4);
    float* aD2  = (float*)alloc(40000 * 4);
    size_t zbytes = (size_t)(p - zbase);

    hipMemsetAsync(zbase, 0, zbytes, stream);

    // setup: weight conversions + biasRG + edge count (one dispatch)
    fused0_k<<<TOT_B, 256, 0, stream>>>(
        gat_w, res_w, dec_w, res_b, gat_b, ei, fwhi, dwhi, biasRG, cnt);

    // encoder gemm: fp32 A/B direct (+ merged CSR prefix scan in last y-slice)
    gemm3_k<1, 2, 1, true><<<dim3(157, 3), 256, 0, stream>>>(
        x, enc_w, enc_b, nullptr, Xhi, nullptr, nullptr, nullptr, nullptr, nullptr, NN,
        nullptr, cnt, row_ptr, nullptr, nullptr);

    // layer 1: fused gemm + attn partials (+ merged fill_csr in last y-slice)
    gemm3_k<2, 1, 2, false><<<dim3(157, 17), 256, 0, stream>>>(
        Xhi, fwhi, biasRG, nullptr, xh_b, resb, aS1, aD1, att_src, att_dst, NN,
        ei, nullptr, row_ptr, cursor, csr);
    agg_k<<<10000, 256, 0, stream>>>(row_ptr, csr, aS1, aD1, xh_b, resb, Xhi);

    // layer 2
    gemm3_k<2, 1, 0, false><<<dim3(157, 16), 256, 0, stream>>>(
        Xhi, fwhi, biasRG, nullptr, xh_b, resb, aS2, aD2, att_src, att_dst, NN,
        nullptr, nullptr, nullptr, nullptr, nullptr);
    agg_k<<<10000, 256, 0, stream>>>(row_ptr, csr, aS2, aD2, xh_b, resb, Xhi);

    // decoder
    gemm3_k<0, 1, 0, false><<<dim3(157, 1), 256, 0, stream>>>(
        Xhi, dwhi, dec_b, out, nullptr, nullptr, nullptr, nullptr, nullptr, nullptr, NN,
        nullptr, nullptr, nullptr, nullptr, nullptr);
}